// Round 10
// baseline (493.496 us; speedup 1.0000x reference)
//
#include <hip/hip_runtime.h>
#include <hip/hip_cooperative_groups.h>

namespace cg = cooperative_groups;

#define THREADS 256
#define CTHREADS 1024
#define CBLOCKS 256
#define CAP 128

typedef float floatx4 __attribute__((ext_vector_type(4)));

// ==================== cooperative front-end: phases 0..8 ====================
// 256 blocks x 1024 threads, 1 block/CU. Covers everything except z@z^T.

__global__ __launch_bounds__(CTHREADS, 1) void front_kernel(
    const int* __restrict__ adj_row, const int* __restrict__ adj_col, const float* __restrict__ adj_val,
    const float* __restrict__ X,
    const float* __restrict__ W0, const float* __restrict__ W1, const float* __restrict__ W2,
    const float* __restrict__ W3, const float* __restrict__ W4, const float* __restrict__ W5,
    const float* __restrict__ W6,
    int* __restrict__ nxt, int* __restrict__ ell_c, float* __restrict__ ell_v,
    float* __restrict__ Ya, float* __restrict__ Yb, float* __restrict__ Y16, float* __restrict__ z,
    int N, int E, int K)
{
    cg::grid_group grid = cg::this_grid();
    __shared__ float w[32 * 32];
    const int t = threadIdx.x;
    const int gtid = blockIdx.x * CTHREADS + t;
    const int NT = CBLOCKS * CTHREADS;

    // ---- P0: zero row counters ----
    for (int i = gtid; i < N; i += NT) nxt[i] = 0;
    grid.sync();

    // ---- P1: ELL scatter + gemm0 ----
    for (int e = gtid; e < E; e += NT) {
        int r = adj_row[e];
        int p = atomicAdd(&nxt[r], 1);
        if (p < CAP) {
            ell_c[r * CAP + p] = adj_col[e];
            ell_v[r * CAP + p] = adj_val[e];
        }
    }
    for (int idx = gtid; idx < N * 32; idx += NT) {
        int r = idx >> 5, f = idx & 31;
        const float* xr = X + (size_t)r * K;
        float acc = 0.f;
        for (int k = 0; k < K; k += 4) {
            floatx4 x = *reinterpret_cast<const floatx4*>(xr + k);
            acc = fmaf(x.x, W0[(k + 0) * 32 + f], acc);
            acc = fmaf(x.y, W0[(k + 1) * 32 + f], acc);
            acc = fmaf(x.z, W0[(k + 2) * 32 + f], acc);
            acc = fmaf(x.w, W0[(k + 3) * 32 + f], acc);
        }
        Ya[idx] = acc;
    }
    grid.sync();

    const int group = gtid >> 5;
    const int NG = NT >> 5;
    const int f = t & 31;

    // ---- P2..P6: 5 hidden layers  Y' = relu(A @ Y) @ W  (32->32) ----
    const float* Wl[5] = {W1, W2, W3, W4, W5};
    float* yin = Ya;
    float* yout = Yb;
#pragma unroll
    for (int l = 0; l < 5; ++l) {
        __syncthreads();
        for (int i = t; i < 32 * 32; i += CTHREADS) w[i] = Wl[l][i];
        __syncthreads();
        for (int r = group; r < N; r += NG) {
            int deg = min(nxt[r], CAP);
            int base = r * CAP;
            float acc = 0.f;
            int i = 0;
            for (; i + 4 <= deg; i += 4) {
                int4    cc = *reinterpret_cast<const int4*>(ell_c + base + i);
                floatx4 vv = *reinterpret_cast<const floatx4*>(ell_v + base + i);
                float y0 = yin[(size_t)cc.x * 32 + f];
                float y1 = yin[(size_t)cc.y * 32 + f];
                float y2 = yin[(size_t)cc.z * 32 + f];
                float y3 = yin[(size_t)cc.w * 32 + f];
                acc = fmaf(vv.x, y0, acc);
                acc = fmaf(vv.y, y1, acc);
                acc = fmaf(vv.z, y2, acc);
                acc = fmaf(vv.w, y3, acc);
            }
            for (; i < deg; ++i)
                acc = fmaf(ell_v[base + i], yin[(size_t)ell_c[base + i] * 32 + f], acc);
            float h = fmaxf(acc, 0.f);
            float y = 0.f;
#pragma unroll
            for (int k = 0; k < 32; ++k)
                y = fmaf(__shfl(h, k, 32), w[k * 32 + f], y);
            yout[r * 32 + f] = y;
        }
        grid.sync();
        float* tmp = yin; yin = yout; yout = tmp;
    }

    // ---- P7: Y16 = relu(A @ Y5) @ W6  (32->16) ----
    __syncthreads();
    for (int i = t; i < 32 * 16; i += CTHREADS) w[i] = W6[i];
    __syncthreads();
    for (int r = group; r < N; r += NG) {
        int deg = min(nxt[r], CAP);
        int base = r * CAP;
        float acc = 0.f;
        int i = 0;
        for (; i + 4 <= deg; i += 4) {
            int4    cc = *reinterpret_cast<const int4*>(ell_c + base + i);
            floatx4 vv = *reinterpret_cast<const floatx4*>(ell_v + base + i);
            float y0 = yin[(size_t)cc.x * 32 + f];
            float y1 = yin[(size_t)cc.y * 32 + f];
            float y2 = yin[(size_t)cc.z * 32 + f];
            float y3 = yin[(size_t)cc.w * 32 + f];
            acc = fmaf(vv.x, y0, acc);
            acc = fmaf(vv.y, y1, acc);
            acc = fmaf(vv.z, y2, acc);
            acc = fmaf(vv.w, y3, acc);
        }
        for (; i < deg; ++i)
            acc = fmaf(ell_v[base + i], yin[(size_t)ell_c[base + i] * 32 + f], acc);
        float h = fmaxf(acc, 0.f);
        int fo = f & 15;
        float y = 0.f;
#pragma unroll
        for (int k = 0; k < 32; ++k)
            y = fmaf(__shfl(h, k, 32), w[k * 16 + fo], y);
        if (f < 16) Y16[r * 16 + fo] = y;
    }
    grid.sync();

    // ---- P8: z = A @ Y16 (no relu); 16 lanes per row ----
    {
        const int group16 = gtid >> 4;
        const int NG16 = NT >> 4;
        const int ff = t & 15;
        for (int r = group16; r < N; r += NG16) {
            int deg = min(nxt[r], CAP);
            int base = r * CAP;
            float acc = 0.f;
            int i = 0;
            for (; i + 4 <= deg; i += 4) {
                int4    cc = *reinterpret_cast<const int4*>(ell_c + base + i);
                floatx4 vv = *reinterpret_cast<const floatx4*>(ell_v + base + i);
                float y0 = Y16[(size_t)cc.x * 16 + ff];
                float y1 = Y16[(size_t)cc.y * 16 + ff];
                float y2 = Y16[(size_t)cc.z * 16 + ff];
                float y3 = Y16[(size_t)cc.w * 16 + ff];
                acc = fmaf(vv.x, y0, acc);
                acc = fmaf(vv.y, y1, acc);
                acc = fmaf(vv.z, y2, acc);
                acc = fmaf(vv.w, y3, acc);
            }
            for (; i < deg; ++i)
                acc = fmaf(ell_v[base + i], Y16[(size_t)ell_c[base + i] * 16 + ff], acc);
            z[(size_t)r * 16 + ff] = acc;
        }
    }
}

// ==================== z @ z^T (separate fat dispatch, write-bound) ====================

__global__ void zzt_kernel(const float* __restrict__ z, float* __restrict__ out, int n) {
    __shared__ float zi[32][16];
    const int t = threadIdx.x;
    const int bi = blockIdx.y * 32;
    for (int i = t; i < 512; i += THREADS) {
        int r = i >> 4, c = i & 15;
        zi[r][c] = (bi + r < n) ? z[(size_t)(bi + r) * 16 + c] : 0.f;
    }
    __syncthreads();
    int j0 = blockIdx.x * 1024 + t * 4;
    if (j0 >= n) return;
    float zj[4][16];
#pragma unroll
    for (int jj = 0; jj < 4; ++jj) {
#pragma unroll
        for (int k = 0; k < 16; k += 4) {
            floatx4 v = *reinterpret_cast<const floatx4*>(z + (size_t)(j0 + jj) * 16 + k);
            zj[jj][k] = v.x; zj[jj][k + 1] = v.y; zj[jj][k + 2] = v.z; zj[jj][k + 3] = v.w;
        }
    }
#pragma unroll 4
    for (int i = 0; i < 32; ++i) {
        if (bi + i >= n) break;
        floatx4 o = {0.f, 0.f, 0.f, 0.f};
#pragma unroll
        for (int k = 0; k < 16; ++k) {
            float a = zi[i][k];
            o.x = fmaf(a, zj[0][k], o.x);
            o.y = fmaf(a, zj[1][k], o.y);
            o.z = fmaf(a, zj[2][k], o.z);
            o.w = fmaf(a, zj[3][k], o.w);
        }
        __builtin_nontemporal_store(o, reinterpret_cast<floatx4*>(out + (size_t)(bi + i) * n + j0));
    }
}

// ==================== fallback (R9 multi-kernel path) ====================

__global__ void zero_kernel(int* __restrict__ p, int n) {
    int i = blockIdx.x * blockDim.x + threadIdx.x;
    if (i < n) p[i] = 0;
}

__global__ void build_and_gemm0_kernel(const int* __restrict__ row, const int* __restrict__ col,
                                       const float* __restrict__ val, int* __restrict__ nxt,
                                       int* __restrict__ ell_c, float* __restrict__ ell_v, int E,
                                       const float* __restrict__ X, const float* __restrict__ W0,
                                       float* __restrict__ Y, int n, int K, int gridE) {
    if ((int)blockIdx.x < gridE) {
        int e = blockIdx.x * THREADS + threadIdx.x;
        if (e < E) {
            int r = row[e];
            int p = atomicAdd(&nxt[r], 1);
            if (p < CAP) {
                ell_c[r * CAP + p] = col[e];
                ell_v[r * CAP + p] = val[e];
            }
        }
    } else {
        int idx = (blockIdx.x - gridE) * THREADS + threadIdx.x;
        int r = idx >> 5;
        int f = idx & 31;
        if (r >= n) return;
        const float* xr = X + (size_t)r * K;
        float acc = 0.f;
        for (int k = 0; k < K; k += 4) {
            floatx4 x = *reinterpret_cast<const floatx4*>(xr + k);
            acc = fmaf(x.x, W0[(k + 0) * 32 + f], acc);
            acc = fmaf(x.y, W0[(k + 1) * 32 + f], acc);
            acc = fmaf(x.z, W0[(k + 2) * 32 + f], acc);
            acc = fmaf(x.w, W0[(k + 3) * 32 + f], acc);
        }
        Y[r * 32 + f] = acc;
    }
}

template <int FOUT>
__global__ void fused_spmm_gemm_kernel(const int* __restrict__ nxt, const int* __restrict__ ell_c,
                                       const float* __restrict__ ell_v, const float* __restrict__ Yin,
                                       const float* __restrict__ W, float* __restrict__ Yout, int n) {
    __shared__ float w[32 * FOUT];
    const int t = threadIdx.x;
    for (int i = t; i < 32 * FOUT; i += THREADS) w[i] = W[i];
    __syncthreads();

    int g = (blockIdx.x * THREADS + t) >> 5;
    if (g >= n) return;
    int f = t & 31;
    int deg = min(nxt[g], CAP);
    int base = g * CAP;
    float acc = 0.f;
    int i = 0;
    for (; i + 4 <= deg; i += 4) {
        int4    cc = *reinterpret_cast<const int4*>(ell_c + base + i);
        floatx4 vv = *reinterpret_cast<const floatx4*>(ell_v + base + i);
        float y0 = Yin[(size_t)cc.x * 32 + f];
        float y1 = Yin[(size_t)cc.y * 32 + f];
        float y2 = Yin[(size_t)cc.z * 32 + f];
        float y3 = Yin[(size_t)cc.w * 32 + f];
        acc = fmaf(vv.x, y0, acc);
        acc = fmaf(vv.y, y1, acc);
        acc = fmaf(vv.z, y2, acc);
        acc = fmaf(vv.w, y3, acc);
    }
    for (; i < deg; ++i)
        acc = fmaf(ell_v[base + i], Yin[(size_t)ell_c[base + i] * 32 + f], acc);
    float h = fmaxf(acc, 0.f);

    const int fo = f & (FOUT - 1);
    float y = 0.f;
#pragma unroll
    for (int k = 0; k < 32; ++k)
        y = fmaf(__shfl(h, k, 32), w[k * FOUT + fo], y);
    if (f < FOUT) Yout[(size_t)g * FOUT + f] = y;
}

__global__ void spmm16_kernel(const int* __restrict__ nxt, const int* __restrict__ ell_c,
                              const float* __restrict__ ell_v, const float* __restrict__ Yin,
                              float* __restrict__ Z, int n) {
    int g = (blockIdx.x * THREADS + threadIdx.x) >> 4;
    if (g >= n) return;
    int f = threadIdx.x & 15;
    int deg = min(nxt[g], CAP);
    int base = g * CAP;
    float acc = 0.f;
    int i = 0;
    for (; i + 4 <= deg; i += 4) {
        int4    cc = *reinterpret_cast<const int4*>(ell_c + base + i);
        floatx4 vv = *reinterpret_cast<const floatx4*>(ell_v + base + i);
        float y0 = Yin[(size_t)cc.x * 16 + f];
        float y1 = Yin[(size_t)cc.y * 16 + f];
        float y2 = Yin[(size_t)cc.z * 16 + f];
        float y3 = Yin[(size_t)cc.w * 16 + f];
        acc = fmaf(vv.x, y0, acc);
        acc = fmaf(vv.y, y1, acc);
        acc = fmaf(vv.z, y2, acc);
        acc = fmaf(vv.w, y3, acc);
    }
    for (; i < deg; ++i)
        acc = fmaf(ell_v[base + i], Yin[(size_t)ell_c[base + i] * 16 + f], acc);
    Z[(size_t)g * 16 + f] = acc;
}

// ==================== launch ====================

extern "C" void kernel_launch(void* const* d_in, const int* in_sizes, int n_in,
                              void* d_out, int out_size, void* d_ws, size_t ws_size,
                              hipStream_t stream) {
    const float* features = (const float*)d_in[0];
    const int*   adj_row  = (const int*)d_in[1];
    const int*   adj_col  = (const int*)d_in[2];
    const float* adj_vals = (const float*)d_in[3];
    const float* W0 = (const float*)d_in[4];
    const float* W1 = (const float*)d_in[5];
    const float* W2 = (const float*)d_in[6];
    const float* W3 = (const float*)d_in[7];
    const float* W4 = (const float*)d_in[8];
    const float* W5 = (const float*)d_in[9];
    const float* W6 = (const float*)d_in[10];

    int E = in_sizes[1];
    int K = in_sizes[4] / 32;   // 512
    int N = in_sizes[0] / K;    // 10000

    char* ws = (char*)d_ws;
    size_t off = 0;
    auto alloc = [&](size_t bytes) -> void* {
        void* p = ws + off;
        off = (off + bytes + 255) & ~(size_t)255;
        return p;
    };
    int*   nxt   = (int*)alloc((size_t)N * 4);
    int*   ell_c = (int*)alloc((size_t)N * CAP * 4);
    float* ell_v = (float*)alloc((size_t)N * CAP * 4);
    float* Ya    = (float*)alloc((size_t)N * 32 * 4);
    float* Yb    = (float*)alloc((size_t)N * 32 * 4);
    float* Y16   = (float*)alloc((size_t)N * 16 * 4);
    float* zbuf  = (float*)alloc((size_t)N * 16 * 4);

    float* out = (float*)d_out;
    dim3 zg((N + 1023) / 1024, (N + 31) / 32);

    void* args[] = {
        (void*)&adj_row, (void*)&adj_col, (void*)&adj_vals, (void*)&features,
        (void*)&W0, (void*)&W1, (void*)&W2, (void*)&W3, (void*)&W4, (void*)&W5, (void*)&W6,
        (void*)&nxt, (void*)&ell_c, (void*)&ell_v,
        (void*)&Ya, (void*)&Yb, (void*)&Y16, (void*)&zbuf,
        (void*)&N, (void*)&E, (void*)&K,
    };
    hipError_t err = hipLaunchCooperativeKernel((void*)front_kernel, dim3(CBLOCKS), dim3(CTHREADS),
                                                args, 0, stream);
    if (err == hipSuccess) {
        zzt_kernel<<<zg, THREADS, 0, stream>>>(zbuf, out, N);
        return;
    }

    // -------- fallback: R9 multi-kernel path --------
    const int gridE = (E + THREADS - 1) / THREADS;
    const int gridG = (N * 32 + THREADS - 1) / THREADS;
    const int gridRow = gridG;

    zero_kernel<<<(N + THREADS - 1) / THREADS, THREADS, 0, stream>>>(nxt, N);
    build_and_gemm0_kernel<<<gridE + gridG, THREADS, 0, stream>>>(
        adj_row, adj_col, adj_vals, nxt, ell_c, ell_v, E, features, W0, Ya, N, K, gridE);

    const float* Wh[5] = {W1, W2, W3, W4, W5};
    float* yin = Ya;
    float* yout = Yb;
    for (int l = 0; l < 5; ++l) {
        fused_spmm_gemm_kernel<32><<<gridRow, THREADS, 0, stream>>>(nxt, ell_c, ell_v, yin, Wh[l], yout, N);
        float* tmp = yin; yin = yout; yout = tmp;
    }
    fused_spmm_gemm_kernel<16><<<gridRow, THREADS, 0, stream>>>(nxt, ell_c, ell_v, yin, W6, Y16, N);
    spmm16_kernel<<<(N * 16 + THREADS - 1) / THREADS, THREADS, 0, stream>>>(nxt, ell_c, ell_v, Y16, zbuf, N);

    zzt_kernel<<<zg, THREADS, 0, stream>>>(zbuf, out, N);
}

// Round 11
// 267.567 us; speedup vs baseline: 1.8444x; 1.8444x over previous
//
#include <hip/hip_runtime.h>

#define THREADS 256
#define CAP 128

typedef float floatx4 __attribute__((ext_vector_type(4)));

// ---------------- phase 0: zero row counters ----------------

__global__ void zero_kernel(int* __restrict__ p, int n) {
    int i = blockIdx.x * blockDim.x + threadIdx.x;
    if (i < n) p[i] = 0;
}

// ---------------- phase 1 (merged): ELL scatter  ||  gemm0 ----------------

__global__ void build_and_gemm0_kernel(const int* __restrict__ row, const int* __restrict__ col,
                                       const float* __restrict__ val, int* __restrict__ nxt,
                                       int* __restrict__ ell_c, float* __restrict__ ell_v, int E,
                                       const float* __restrict__ X, const float* __restrict__ W0,
                                       float* __restrict__ Y, int n, int K, int gridE) {
    if ((int)blockIdx.x < gridE) {
        int e = blockIdx.x * THREADS + threadIdx.x;
        if (e < E) {
            int r = row[e];
            int p = atomicAdd(&nxt[r], 1);
            if (p < CAP) {
                ell_c[r * CAP + p] = col[e];
                ell_v[r * CAP + p] = val[e];
            }
        }
    } else {
        int idx = (blockIdx.x - gridE) * THREADS + threadIdx.x;
        int r = idx >> 5;
        int f = idx & 31;
        if (r >= n) return;
        const float* xr = X + (size_t)r * K;
        float acc = 0.f;
        for (int k = 0; k < K; k += 4) {
            floatx4 x = *reinterpret_cast<const floatx4*>(xr + k);
            acc = fmaf(x.x, W0[(k + 0) * 32 + f], acc);
            acc = fmaf(x.y, W0[(k + 1) * 32 + f], acc);
            acc = fmaf(x.z, W0[(k + 2) * 32 + f], acc);
            acc = fmaf(x.w, W0[(k + 3) * 32 + f], acc);
        }
        Y[r * 32 + f] = acc;
    }
}

// ---------------- fused SpMM(+relu) + 32xFOUT GEMM ----------------

template <int FOUT>
__global__ void fused_spmm_gemm_kernel(const int* __restrict__ nxt, const int* __restrict__ ell_c,
                                       const float* __restrict__ ell_v, const float* __restrict__ Yin,
                                       const float* __restrict__ W, float* __restrict__ Yout, int n) {
    __shared__ float w[32 * FOUT];
    const int t = threadIdx.x;
    for (int i = t; i < 32 * FOUT; i += THREADS) w[i] = W[i];
    __syncthreads();

    int g = (blockIdx.x * THREADS + t) >> 5;
    if (g >= n) return;
    int f = t & 31;
    int deg = min(nxt[g], CAP);
    int base = g * CAP;
    float acc = 0.f;
    int i = 0;
    for (; i + 4 <= deg; i += 4) {
        int4    cc = *reinterpret_cast<const int4*>(ell_c + base + i);
        floatx4 vv = *reinterpret_cast<const floatx4*>(ell_v + base + i);
        float y0 = Yin[(size_t)cc.x * 32 + f];
        float y1 = Yin[(size_t)cc.y * 32 + f];
        float y2 = Yin[(size_t)cc.z * 32 + f];
        float y3 = Yin[(size_t)cc.w * 32 + f];
        acc = fmaf(vv.x, y0, acc);
        acc = fmaf(vv.y, y1, acc);
        acc = fmaf(vv.z, y2, acc);
        acc = fmaf(vv.w, y3, acc);
    }
    for (; i < deg; ++i)
        acc = fmaf(ell_v[base + i], Yin[(size_t)ell_c[base + i] * 32 + f], acc);
    float h = fmaxf(acc, 0.f);

    const int fo = f & (FOUT - 1);
    float y = 0.f;
#pragma unroll
    for (int k = 0; k < 32; ++k)
        y = fmaf(__shfl(h, k, 32), w[k * FOUT + fo], y);
    if (f < FOUT) Yout[(size_t)g * FOUT + f] = y;
}

// final z = A @ Y16 (no relu); 16 lanes per row
__global__ void spmm16_kernel(const int* __restrict__ nxt, const int* __restrict__ ell_c,
                              const float* __restrict__ ell_v, const float* __restrict__ Yin,
                              float* __restrict__ Z, int n) {
    int g = (blockIdx.x * THREADS + threadIdx.x) >> 4;
    if (g >= n) return;
    int f = threadIdx.x & 15;
    int deg = min(nxt[g], CAP);
    int base = g * CAP;
    float acc = 0.f;
    int i = 0;
    for (; i + 4 <= deg; i += 4) {
        int4    cc = *reinterpret_cast<const int4*>(ell_c + base + i);
        floatx4 vv = *reinterpret_cast<const floatx4*>(ell_v + base + i);
        float y0 = Yin[(size_t)cc.x * 16 + f];
        float y1 = Yin[(size_t)cc.y * 16 + f];
        float y2 = Yin[(size_t)cc.z * 16 + f];
        float y3 = Yin[(size_t)cc.w * 16 + f];
        acc = fmaf(vv.x, y0, acc);
        acc = fmaf(vv.y, y1, acc);
        acc = fmaf(vv.z, y2, acc);
        acc = fmaf(vv.w, y3, acc);
    }
    for (; i < deg; ++i)
        acc = fmaf(ell_v[base + i], Yin[(size_t)ell_c[base + i] * 16 + f], acc);
    Z[(size_t)g * 16 + f] = acc;
}

// ---------------- z @ z^T ----------------
// Plain (L2-mediated) float4 stores: nontemporal sc0/sc1 16B writes bypassed
// L2 write-combining and capped write BW ~2 TB/s (R9 inference).

__global__ void zzt_kernel(const float* __restrict__ z, float* __restrict__ out, int n) {
    __shared__ float zi[32][16];
    const int t = threadIdx.x;
    const int bi = blockIdx.y * 32;
    for (int i = t; i < 512; i += THREADS) {
        int r = i >> 4, c = i & 15;
        zi[r][c] = (bi + r < n) ? z[(size_t)(bi + r) * 16 + c] : 0.f;
    }
    __syncthreads();
    int j0 = blockIdx.x * 1024 + t * 4;
    if (j0 >= n) return;
    float zj[4][16];
#pragma unroll
    for (int jj = 0; jj < 4; ++jj) {
#pragma unroll
        for (int k = 0; k < 16; k += 4) {
            floatx4 v = *reinterpret_cast<const floatx4*>(z + (size_t)(j0 + jj) * 16 + k);
            zj[jj][k] = v.x; zj[jj][k + 1] = v.y; zj[jj][k + 2] = v.z; zj[jj][k + 3] = v.w;
        }
    }
#pragma unroll 4
    for (int i = 0; i < 32; ++i) {
        if (bi + i >= n) break;
        floatx4 o = {0.f, 0.f, 0.f, 0.f};
#pragma unroll
        for (int k = 0; k < 16; ++k) {
            float a = zi[i][k];
            o.x = fmaf(a, zj[0][k], o.x);
            o.y = fmaf(a, zj[1][k], o.y);
            o.z = fmaf(a, zj[2][k], o.z);
            o.w = fmaf(a, zj[3][k], o.w);
        }
        *reinterpret_cast<floatx4*>(out + (size_t)(bi + i) * n + j0) = o;
    }
}

// ---------------- launch ----------------

extern "C" void kernel_launch(void* const* d_in, const int* in_sizes, int n_in,
                              void* d_out, int out_size, void* d_ws, size_t ws_size,
                              hipStream_t stream) {
    const float* features = (const float*)d_in[0];
    const int*   adj_row  = (const int*)d_in[1];
    const int*   adj_col  = (const int*)d_in[2];
    const float* adj_vals = (const float*)d_in[3];
    const float* W0 = (const float*)d_in[4];
    const float* Wh[5] = {(const float*)d_in[5], (const float*)d_in[6], (const float*)d_in[7],
                          (const float*)d_in[8], (const float*)d_in[9]};
    const float* W6 = (const float*)d_in[10];

    const int E = in_sizes[1];
    const int K = in_sizes[4] / 32;   // 512
    const int N = in_sizes[0] / K;    // 10000

    char* ws = (char*)d_ws;
    size_t off = 0;
    auto alloc = [&](size_t bytes) -> void* {
        void* p = ws + off;
        off = (off + bytes + 255) & ~(size_t)255;
        return p;
    };
    int*   nxt   = (int*)alloc((size_t)N * 4);
    int*   ell_c = (int*)alloc((size_t)N * CAP * 4);
    float* ell_v = (float*)alloc((size_t)N * CAP * 4);
    float* Ya    = (float*)alloc((size_t)N * 32 * 4);
    float* Yb    = (float*)alloc((size_t)N * 32 * 4);
    float* Y16   = (float*)alloc((size_t)N * 16 * 4);
    float* zbuf  = (float*)alloc((size_t)N * 16 * 4);

    const int gridE = (E + THREADS - 1) / THREADS;
    const int gridG = (N * 32 + THREADS - 1) / THREADS;
    const int gridRow = gridG;

    zero_kernel<<<(N + THREADS - 1) / THREADS, THREADS, 0, stream>>>(nxt, N);
    build_and_gemm0_kernel<<<gridE + gridG, THREADS, 0, stream>>>(
        adj_row, adj_col, adj_vals, nxt, ell_c, ell_v, E, features, W0, Ya, N, K, gridE);

    float* yin = Ya;
    float* yout = Yb;
    for (int l = 0; l < 5; ++l) {
        fused_spmm_gemm_kernel<32><<<gridRow, THREADS, 0, stream>>>(nxt, ell_c, ell_v, yin, Wh[l], yout, N);
        float* tmp = yin; yin = yout; yout = tmp;
    }
    fused_spmm_gemm_kernel<16><<<gridRow, THREADS, 0, stream>>>(nxt, ell_c, ell_v, yin, W6, Y16, N);
    spmm16_kernel<<<(N * 16 + THREADS - 1) / THREADS, THREADS, 0, stream>>>(nxt, ell_c, ell_v, Y16, zbuf, N);

    dim3 zg((N + 1023) / 1024, (N + 31) / 32);
    zzt_kernel<<<zg, THREADS, 0, stream>>>(zbuf, (float*)d_out, N);
}

// Round 12
// 243.074 us; speedup vs baseline: 2.0302x; 1.1008x over previous
//
#include <hip/hip_runtime.h>

#define THREADS 256
#define CAP 128

typedef float floatx4 __attribute__((ext_vector_type(4)));

// ---------------- phase 0: zero row counters ----------------

__global__ void zero_kernel(int* __restrict__ p, int n) {
    int i = blockIdx.x * blockDim.x + threadIdx.x;
    if (i < n) p[i] = 0;
}

// ---------------- phase 1 (merged): ELL scatter  ||  gemm0 ----------------

__global__ void build_and_gemm0_kernel(const int* __restrict__ row, const int* __restrict__ col,
                                       const float* __restrict__ val, int* __restrict__ nxt,
                                       int* __restrict__ ell_c, float* __restrict__ ell_v, int E,
                                       const float* __restrict__ X, const float* __restrict__ W0,
                                       float* __restrict__ Y, int n, int K, int gridE) {
    if ((int)blockIdx.x < gridE) {
        int e = blockIdx.x * THREADS + threadIdx.x;
        if (e < E) {
            int r = row[e];
            int p = atomicAdd(&nxt[r], 1);
            if (p < CAP) {
                ell_c[r * CAP + p] = col[e];
                ell_v[r * CAP + p] = val[e];
            }
        }
    } else {
        int idx = (blockIdx.x - gridE) * THREADS + threadIdx.x;
        int r = idx >> 5;
        int f = idx & 31;
        if (r >= n) return;
        const float* xr = X + (size_t)r * K;
        float acc = 0.f;
        for (int k = 0; k < K; k += 4) {
            floatx4 x = *reinterpret_cast<const floatx4*>(xr + k);
            acc = fmaf(x.x, W0[(k + 0) * 32 + f], acc);
            acc = fmaf(x.y, W0[(k + 1) * 32 + f], acc);
            acc = fmaf(x.z, W0[(k + 2) * 32 + f], acc);
            acc = fmaf(x.w, W0[(k + 3) * 32 + f], acc);
        }
        Y[r * 32 + f] = acc;
    }
}

// ---------------- fused SpMM(+relu) + 32xFOUT GEMM ----------------
// 8-wide gather pipelining: 8 independent 128B gathers in flight / iter.

template <int FOUT>
__global__ void fused_spmm_gemm_kernel(const int* __restrict__ nxt, const int* __restrict__ ell_c,
                                       const float* __restrict__ ell_v, const float* __restrict__ Yin,
                                       const float* __restrict__ W, float* __restrict__ Yout, int n) {
    __shared__ float w[32 * FOUT];
    const int t = threadIdx.x;
    for (int i = t; i < 32 * FOUT; i += THREADS) w[i] = W[i];
    __syncthreads();

    int g = (blockIdx.x * THREADS + t) >> 5;
    if (g >= n) return;
    int f = t & 31;
    int deg = min(nxt[g], CAP);
    int base = g * CAP;
    float acc = 0.f;
    int i = 0;
    for (; i + 8 <= deg; i += 8) {
        int4    cc0 = *reinterpret_cast<const int4*>(ell_c + base + i);
        int4    cc1 = *reinterpret_cast<const int4*>(ell_c + base + i + 4);
        floatx4 vv0 = *reinterpret_cast<const floatx4*>(ell_v + base + i);
        floatx4 vv1 = *reinterpret_cast<const floatx4*>(ell_v + base + i + 4);
        float y0 = Yin[(size_t)cc0.x * 32 + f];
        float y1 = Yin[(size_t)cc0.y * 32 + f];
        float y2 = Yin[(size_t)cc0.z * 32 + f];
        float y3 = Yin[(size_t)cc0.w * 32 + f];
        float y4 = Yin[(size_t)cc1.x * 32 + f];
        float y5 = Yin[(size_t)cc1.y * 32 + f];
        float y6 = Yin[(size_t)cc1.z * 32 + f];
        float y7 = Yin[(size_t)cc1.w * 32 + f];
        acc = fmaf(vv0.x, y0, acc);
        acc = fmaf(vv0.y, y1, acc);
        acc = fmaf(vv0.z, y2, acc);
        acc = fmaf(vv0.w, y3, acc);
        acc = fmaf(vv1.x, y4, acc);
        acc = fmaf(vv1.y, y5, acc);
        acc = fmaf(vv1.z, y6, acc);
        acc = fmaf(vv1.w, y7, acc);
    }
    for (; i + 4 <= deg; i += 4) {
        int4    cc = *reinterpret_cast<const int4*>(ell_c + base + i);
        floatx4 vv = *reinterpret_cast<const floatx4*>(ell_v + base + i);
        float y0 = Yin[(size_t)cc.x * 32 + f];
        float y1 = Yin[(size_t)cc.y * 32 + f];
        float y2 = Yin[(size_t)cc.z * 32 + f];
        float y3 = Yin[(size_t)cc.w * 32 + f];
        acc = fmaf(vv.x, y0, acc);
        acc = fmaf(vv.y, y1, acc);
        acc = fmaf(vv.z, y2, acc);
        acc = fmaf(vv.w, y3, acc);
    }
    for (; i < deg; ++i)
        acc = fmaf(ell_v[base + i], Yin[(size_t)ell_c[base + i] * 32 + f], acc);
    float h = fmaxf(acc, 0.f);

    const int fo = f & (FOUT - 1);
    float y = 0.f;
#pragma unroll
    for (int k = 0; k < 32; ++k)
        y = fmaf(__shfl(h, k, 32), w[k * FOUT + fo], y);
    if (f < FOUT) Yout[(size_t)g * FOUT + f] = y;
}

// final z = A @ Y16 (no relu); 16 lanes per row, 8-wide gathers
__global__ void spmm16_kernel(const int* __restrict__ nxt, const int* __restrict__ ell_c,
                              const float* __restrict__ ell_v, const float* __restrict__ Yin,
                              float* __restrict__ Z, int n) {
    int g = (blockIdx.x * blockDim.x + threadIdx.x) >> 4;
    if (g >= n) return;
    int f = threadIdx.x & 15;
    int deg = min(nxt[g], CAP);
    int base = g * CAP;
    float acc = 0.f;
    int i = 0;
    for (; i + 8 <= deg; i += 8) {
        int4    cc0 = *reinterpret_cast<const int4*>(ell_c + base + i);
        int4    cc1 = *reinterpret_cast<const int4*>(ell_c + base + i + 4);
        floatx4 vv0 = *reinterpret_cast<const floatx4*>(ell_v + base + i);
        floatx4 vv1 = *reinterpret_cast<const floatx4*>(ell_v + base + i + 4);
        float y0 = Yin[(size_t)cc0.x * 16 + f];
        float y1 = Yin[(size_t)cc0.y * 16 + f];
        float y2 = Yin[(size_t)cc0.z * 16 + f];
        float y3 = Yin[(size_t)cc0.w * 16 + f];
        float y4 = Yin[(size_t)cc1.x * 16 + f];
        float y5 = Yin[(size_t)cc1.y * 16 + f];
        float y6 = Yin[(size_t)cc1.z * 16 + f];
        float y7 = Yin[(size_t)cc1.w * 16 + f];
        acc = fmaf(vv0.x, y0, acc);
        acc = fmaf(vv0.y, y1, acc);
        acc = fmaf(vv0.z, y2, acc);
        acc = fmaf(vv0.w, y3, acc);
        acc = fmaf(vv1.x, y4, acc);
        acc = fmaf(vv1.y, y5, acc);
        acc = fmaf(vv1.z, y6, acc);
        acc = fmaf(vv1.w, y7, acc);
    }
    for (; i + 4 <= deg; i += 4) {
        int4    cc = *reinterpret_cast<const int4*>(ell_c + base + i);
        floatx4 vv = *reinterpret_cast<const floatx4*>(ell_v + base + i);
        acc = fmaf(vv.x, Yin[(size_t)cc.x * 16 + f], acc);
        acc = fmaf(vv.y, Yin[(size_t)cc.y * 16 + f], acc);
        acc = fmaf(vv.z, Yin[(size_t)cc.z * 16 + f], acc);
        acc = fmaf(vv.w, Yin[(size_t)cc.w * 16 + f], acc);
    }
    for (; i < deg; ++i)
        acc = fmaf(ell_v[base + i], Yin[(size_t)ell_c[base + i] * 16 + f], acc);
    Z[(size_t)g * 16 + f] = acc;
}

// ---------------- z @ z^T ----------------
// nt float4 stores: R9 vs R11 A/B showed nt = -18us (L2-bypass wins for the
// pure 400MB write stream).

__global__ void zzt_kernel(const float* __restrict__ z, float* __restrict__ out, int n) {
    __shared__ float zi[32][16];
    const int t = threadIdx.x;
    const int bi = blockIdx.y * 32;
    for (int i = t; i < 512; i += THREADS) {
        int r = i >> 4, c = i & 15;
        zi[r][c] = (bi + r < n) ? z[(size_t)(bi + r) * 16 + c] : 0.f;
    }
    __syncthreads();
    int j0 = blockIdx.x * 1024 + t * 4;
    if (j0 >= n) return;
    float zj[4][16];
#pragma unroll
    for (int jj = 0; jj < 4; ++jj) {
#pragma unroll
        for (int k = 0; k < 16; k += 4) {
            floatx4 v = *reinterpret_cast<const floatx4*>(z + (size_t)(j0 + jj) * 16 + k);
            zj[jj][k] = v.x; zj[jj][k + 1] = v.y; zj[jj][k + 2] = v.z; zj[jj][k + 3] = v.w;
        }
    }
#pragma unroll 4
    for (int i = 0; i < 32; ++i) {
        if (bi + i >= n) break;
        floatx4 o = {0.f, 0.f, 0.f, 0.f};
#pragma unroll
        for (int k = 0; k < 16; ++k) {
            float a = zi[i][k];
            o.x = fmaf(a, zj[0][k], o.x);
            o.y = fmaf(a, zj[1][k], o.y);
            o.z = fmaf(a, zj[2][k], o.z);
            o.w = fmaf(a, zj[3][k], o.w);
        }
        __builtin_nontemporal_store(o, reinterpret_cast<floatx4*>(out + (size_t)(bi + i) * n + j0));
    }
}

// ---------------- launch ----------------

extern "C" void kernel_launch(void* const* d_in, const int* in_sizes, int n_in,
                              void* d_out, int out_size, void* d_ws, size_t ws_size,
                              hipStream_t stream) {
    const float* features = (const float*)d_in[0];
    const int*   adj_row  = (const int*)d_in[1];
    const int*   adj_col  = (const int*)d_in[2];
    const float* adj_vals = (const float*)d_in[3];
    const float* W0 = (const float*)d_in[4];
    const float* Wh[5] = {(const float*)d_in[5], (const float*)d_in[6], (const float*)d_in[7],
                          (const float*)d_in[8], (const float*)d_in[9]};
    const float* W6 = (const float*)d_in[10];

    const int E = in_sizes[1];
    const int K = in_sizes[4] / 32;   // 512
    const int N = in_sizes[0] / K;    // 10000

    char* ws = (char*)d_ws;
    size_t off = 0;
    auto alloc = [&](size_t bytes) -> void* {
        void* p = ws + off;
        off = (off + bytes + 255) & ~(size_t)255;
        return p;
    };
    int*   nxt   = (int*)alloc((size_t)N * 4);
    int*   ell_c = (int*)alloc((size_t)N * CAP * 4);
    float* ell_v = (float*)alloc((size_t)N * CAP * 4);
    float* Ya    = (float*)alloc((size_t)N * 32 * 4);
    float* Yb    = (float*)alloc((size_t)N * 32 * 4);
    float* Y16   = (float*)alloc((size_t)N * 16 * 4);
    float* zbuf  = (float*)alloc((size_t)N * 16 * 4);

    const int gridE = (E + THREADS - 1) / THREADS;
    const int gridG = (N * 32 + THREADS - 1) / THREADS;
    const int gridRow = gridG;

    zero_kernel<<<(N + THREADS - 1) / THREADS, THREADS, 0, stream>>>(nxt, N);
    build_and_gemm0_kernel<<<gridE + gridG, THREADS, 0, stream>>>(
        adj_row, adj_col, adj_vals, nxt, ell_c, ell_v, E, features, W0, Ya, N, K, gridE);

    float* yin = Ya;
    float* yout = Yb;
    for (int l = 0; l < 5; ++l) {
        fused_spmm_gemm_kernel<32><<<gridRow, THREADS, 0, stream>>>(nxt, ell_c, ell_v, yin, Wh[l], yout, N);
        float* tmp = yin; yin = yout; yout = tmp;
    }
    fused_spmm_gemm_kernel<16><<<gridRow, THREADS, 0, stream>>>(nxt, ell_c, ell_v, yin, W6, Y16, N);
    spmm16_kernel<<<(N * 16 + THREADS - 1) / THREADS, THREADS, 0, stream>>>(nxt, ell_c, ell_v, Y16, zbuf, N);

    dim3 zg((N + 1023) / 1024, (N + 31) / 32);
    zzt_kernel<<<zg, THREADS, 0, stream>>>(zbuf, (float*)d_out, N);
}